// Round 15
// baseline (7598.163 us; speedup 1.0000x reference)
//
#include <hip/hip_runtime.h>
#include <hip/hip_cooperative_groups.h>

namespace cg = cooperative_groups;

#define B_     512
#define T_     48
#define FRAME_ 2048
#define PROJ_  512
#define MID_   128
#define HID_   1024
#define G4_    4096

typedef unsigned short u16;
typedef __bf16 bf16x8 __attribute__((ext_vector_type(8)));
typedef float  f32x4  __attribute__((ext_vector_type(4)));

__device__ __forceinline__ float sigmoidf_(float x) {
    return 1.0f / (1.0f + expf(-x));
}
__device__ __forceinline__ u16 f2bf_rn(float f) {
    unsigned int u = __float_as_uint(f);
    u += 0x7fffu + ((u >> 16) & 1u);
    return (u16)(u >> 16);
}
__device__ __forceinline__ float bf2f(u16 s) {
    return __uint_as_float(((unsigned int)s) << 16);
}
__device__ __forceinline__ void gld16(const void* g, void* l) {
    __builtin_amdgcn_global_load_lds((const __attribute__((address_space(1))) void*)g,
                                     (__attribute__((address_space(3))) void*)l, 16, 0, 0);
}
__device__ __forceinline__ uint4 pack8(const u16* h) {
    return make_uint4((unsigned)h[0] | ((unsigned)h[1] << 16),
                      (unsigned)h[2] | ((unsigned)h[3] << 16),
                      (unsigned)h[4] | ((unsigned)h[5] << 16),
                      (unsigned)h[6] | ((unsigned)h[7] << 16));
}

// ---------------------------------------------------------------------------
// BD linearization precompute (exact fp64 path)
// ---------------------------------------------------------------------------
__global__ void wvec_kernel(const float* __restrict__ Wsi, const float* __restrict__ Wsh,
                            const float* __restrict__ vs,
                            double* __restrict__ wsi_vd, float* __restrict__ wsh_v)
{
    const int gid = blockIdx.x * 256 + threadIdx.x;
    if (gid < 512) {
        double s = 0.0;
        for (int mi = 0; mi < MID_; ++mi)
            s += (double)vs[mi] * (double)Wsi[(size_t)mi * PROJ_ + gid];
        wsi_vd[gid] = s;
    } else if (gid < 1536) {
        const int k = gid - 512;
        double s = 0.0;
        for (int mi = 0; mi < MID_; ++mi)
            s += (double)vs[mi] * (double)Wsh[(size_t)mi * HID_ + k];
        wsh_v[k] = (float)s;
    }
}

__global__ void cc_kernel(const float* __restrict__ be, const double* __restrict__ wsi_vd,
                          const float* __restrict__ vs, const float* __restrict__ bbd,
                          double* __restrict__ cc)
{
    __shared__ double red[256];
    const int tid = threadIdx.x;
    double s = 0.0;
    for (int p = tid; p < PROJ_; p += 256) s += (double)be[p] * wsi_vd[p];
    red[tid] = s;
    __syncthreads();
    for (int st = 128; st > 0; st >>= 1) {
        if (tid < st) red[tid] += red[tid + st];
        __syncthreads();
    }
    if (tid == 0) {
        double b = 0.0;
        for (int mi = 0; mi < MID_; ++mi) b += (double)vs[mi] * (double)bbd[mi];
        cc[0] = red[0] + b;
    }
}

__global__ void u_kernel(const float* __restrict__ We, const double* __restrict__ wsi_vd,
                         double* __restrict__ u)
{
    const int f = blockIdx.x * 256 + threadIdx.x;   // 2048
    double s = 0.0;
    for (int p = 0; p < PROJ_; ++p)
        s += wsi_vd[p] * (double)We[(size_t)p * FRAME_ + f];
    u[f] = s;
}

// ---------------------------------------------------------------------------
// vidpack: video fp32 -> packed bf16 hi/lo planes  vid'[g][row], g=k-octet
// Fused: Lv[t][b] = video[row]·u + cc   (fp64)
// ---------------------------------------------------------------------------
__global__ __launch_bounds__(256)
void vidpack_kernel(const float* __restrict__ video, const double* __restrict__ u,
                    const double* __restrict__ cc,
                    u16* __restrict__ phi, u16* __restrict__ plo,
                    float* __restrict__ Lv)
{
    __shared__ double red[16][17];
    const int tid = threadIdx.x;
    const int r   = tid & 15, kq = tid >> 4;
    const int row = blockIdx.x * 16 + r;
    const float* vr = video + (size_t)row * FRAME_;
    double s = 0.0;
#pragma unroll
    for (int j = 0; j < 16; ++j) {
        const int k0 = kq * 128 + j * 8;
        const float4 a = *(const float4*)&vr[k0];
        const float4 b = *(const float4*)&vr[k0 + 4];
        const float f[8] = {a.x, a.y, a.z, a.w, b.x, b.y, b.z, b.w};
        s += (double)f[0]*u[k0+0] + (double)f[1]*u[k0+1] + (double)f[2]*u[k0+2]
           + (double)f[3]*u[k0+3] + (double)f[4]*u[k0+4] + (double)f[5]*u[k0+5]
           + (double)f[6]*u[k0+6] + (double)f[7]*u[k0+7];
        u16 h[8], l[8];
#pragma unroll
        for (int e = 0; e < 8; ++e) {
            h[e] = f2bf_rn(f[e]);
            l[e] = f2bf_rn(f[e] - bf2f(h[e]));
        }
        const int g = kq * 16 + j;
        const size_t off = ((size_t)g * 24576 + row) * 16;
        *(uint4*)((char*)phi + off) = pack8(h);
        *(uint4*)((char*)plo + off) = pack8(l);
    }
    red[r][kq] = s;
    __syncthreads();
    if (tid < 16) {
        double t = 0.0;
#pragma unroll
        for (int q = 0; q < 16; ++q) t += red[tid][q];
        const int rw = blockIdx.x * 16 + tid;
        Lv[(rw % T_) * B_ + rw / T_] = (float)(t + cc[0]);
    }
}

// ---------------------------------------------------------------------------
// wepack: We -> packed planes  We'[by][kk][ko*128+n]
// ---------------------------------------------------------------------------
__global__ void wepack_kernel(const float* __restrict__ We,
                              u16* __restrict__ phi, u16* __restrict__ plo)
{
    const int kk = blockIdx.x, by = blockIdx.y, tid = threadIdx.x;
#pragma unroll
    for (int pass = 0; pass < 2; ++pass) {
        const int g = tid + pass * 256;
        const int ko = g >> 7, n = g & 127;
        const int p = by * 128 + n;
        const int k = kk * 32 + ko * 8;
        const float4 a = *(const float4*)&We[(size_t)p * FRAME_ + k];
        const float4 b = *(const float4*)&We[(size_t)p * FRAME_ + k + 4];
        const float f[8] = {a.x, a.y, a.z, a.w, b.x, b.y, b.z, b.w};
        u16 h[8], l[8];
#pragma unroll
        for (int e = 0; e < 8; ++e) {
            h[e] = f2bf_rn(f[e]);
            l[e] = f2bf_rn(f[e] - bf2f(h[e]));
        }
        const size_t off = (((size_t)by * 64 + kk) * 512 + g) * 16;
        *(uint4*)((char*)phi + off) = pack8(h);
        *(uint4*)((char*)plo + off) = pack8(l);
    }
}

// ---------------------------------------------------------------------------
// wihpack / whhpack: W1 (gate-interleaved n) -> packed planes
// ---------------------------------------------------------------------------
__global__ void wihpack_kernel(const float* __restrict__ Wih,
                               u16* __restrict__ phi, u16* __restrict__ plo)
{
    const int kk = blockIdx.x, by = blockIdx.y, tid = threadIdx.x;
#pragma unroll
    for (int pass = 0; pass < 2; ++pass) {
        const int g = tid + pass * 256;
        const int ko = g >> 7, n = g & 127;
        const int gate = n & 3, hl = n >> 2;
        const int srow = gate * HID_ + by * 32 + hl;
        const int k = kk * 32 + ko * 8;
        const float4 a = *(const float4*)&Wih[(size_t)srow * PROJ_ + k];
        const float4 b = *(const float4*)&Wih[(size_t)srow * PROJ_ + k + 4];
        const float f[8] = {a.x, a.y, a.z, a.w, b.x, b.y, b.z, b.w};
        u16 h[8], l[8];
#pragma unroll
        for (int e = 0; e < 8; ++e) {
            h[e] = f2bf_rn(f[e]);
            l[e] = f2bf_rn(f[e] - bf2f(h[e]));
        }
        const size_t off = (((size_t)by * 16 + kk) * 512 + g) * 16;
        *(uint4*)((char*)phi + off) = pack8(h);
        *(uint4*)((char*)plo + off) = pack8(l);
    }
}

__global__ void whhpack_kernel(const float* __restrict__ Whh,
                               u16* __restrict__ phi, u16* __restrict__ plo)
{
    const int kk = blockIdx.x, by = blockIdx.y, tid = threadIdx.x;
#pragma unroll
    for (int pass = 0; pass < 2; ++pass) {
        const int g = tid + pass * 256;
        const int ko = g >> 7, n = g & 127;
        const int gate = n & 3, hl = n >> 2;
        const int srow = gate * HID_ + by * 32 + hl;
        const int k = kk * 32 + ko * 8;
        const float4 a = *(const float4*)&Whh[(size_t)srow * HID_ + k];
        const float4 b = *(const float4*)&Whh[(size_t)srow * HID_ + k + 4];
        const float f[8] = {a.x, a.y, a.z, a.w, b.x, b.y, b.z, b.w};
        u16 h[8], l[8];
#pragma unroll
        for (int e = 0; e < 8; ++e) {
            h[e] = f2bf_rn(f[e]);
            l[e] = f2bf_rn(f[e] - bf2f(h[e]));
        }
        const size_t off = (((size_t)by * 32 + kk) * 512 + g) * 16;
        *(uint4*)((char*)phi + off) = pack8(h);
        *(uint4*)((char*)plo + off) = pack8(l);
    }
}

// b1g: gate-interleaved bias vector (added once into Gx)
__global__ void b1g_kernel(const float* __restrict__ bih, const float* __restrict__ bhh,
                           float* __restrict__ b1g)
{
    const int n = blockIdx.x * 256 + threadIdx.x;   // 4096
    const int by = n >> 7, nl = n & 127;
    const int gate = nl & 3, hl = nl >> 2;
    const int src = gate * HID_ + by * 32 + hl;
    b1g[n] = bih[src] + bhh[src];
}

// ===========================================================================
// 128x128-tile GEMMs: 256 threads = 4 waves, 64x64 wave tiles,
// A+B LDS double-buffered, 2-barrier protocol per iter.  (R14-proven)
// ===========================================================================

// ---------------------------------------------------------------------------
// embed GEMM: vt = video @ We^T + be -> vt' packed planes. NK=64, grid 768.
// ---------------------------------------------------------------------------
__global__ __launch_bounds__(256, 2)
void embed_mfma_kernel(const u16* __restrict__ Ahi_g, const u16* __restrict__ Alo_g,
                       const u16* __restrict__ Bhi_g, const u16* __restrict__ Blo_g,
                       const float* __restrict__ be,
                       u16* __restrict__ vphi, u16* __restrict__ vplo)
{
    __shared__ char smem[65536];
    const int tid = threadIdx.x;
    const int xcd = blockIdx.x & 7, s_ = blockIdx.x >> 3;   // 768 blocks, s_<96
    const int by = s_ & 3, bx = xcd * 24 + (s_ >> 2);
    const int n0 = by * 128, row0 = bx * 128;
    const int w = tid >> 6, l = tid & 63, lm = l & 15, ko4 = l >> 4;
    const int wr = (w >> 1) * 64, wc = (w & 1) * 64;

    const char* aS[4]; const char* bS[4]; int loff[4];
#pragma unroll
    for (int i = 0; i < 4; ++i) {
        const int j = w * 4 + i;
        const int ip = (j & 7) * 64 + l;
        const int ko = ip >> 7, rc = ip & 127;
        const char* ab = (j >> 3) ? (const char*)Alo_g : (const char*)Ahi_g;
        aS[i] = ab + ((size_t)ko * 24576 + row0 + rc) * 16;
        const char* bb = (j >> 3) ? (const char*)Blo_g : (const char*)Bhi_g;
        bS[i] = bb + (size_t)by * 524288 + (size_t)ip * 16;
        loff[i] = j * 1024 + l * 16;
    }

    f32x4 acc[4][4] = {};
#pragma unroll
    for (int i = 0; i < 4; ++i) {
        gld16(aS[i], smem + loff[i]);
        gld16(bS[i], smem + 16384 + loff[i]);
    }

#pragma unroll 2
    for (int kk = 0; kk < 64; ++kk) {
        if (kk + 1 < 64) {
            const int bo = ((kk + 1) & 1) * 32768;
#pragma unroll
            for (int i = 0; i < 4; ++i) {
                gld16(aS[i] + (size_t)(kk + 1) * 1572864, smem + bo + loff[i]);
                gld16(bS[i] + (size_t)(kk + 1) * 8192,    smem + bo + 16384 + loff[i]);
            }
            asm volatile("s_waitcnt vmcnt(8)\ns_barrier" ::: "memory");
        } else {
            asm volatile("s_waitcnt vmcnt(0)\ns_barrier" ::: "memory");
        }
        __builtin_amdgcn_sched_barrier(0);

        const char* rb = smem + (kk & 1) * 32768;
        bf16x8 Ah[4], Al[4], Bh[4], Bl[4];
#pragma unroll
        for (int mt = 0; mt < 4; ++mt) {
            const int idx = (ko4 * 128 + wr + mt * 16 + lm) * 16;
            Ah[mt] = *(const bf16x8*)(rb + idx);
            Al[mt] = *(const bf16x8*)(rb + 8192 + idx);
        }
#pragma unroll
        for (int nt = 0; nt < 4; ++nt) {
            const int idx = (ko4 * 128 + wc + nt * 16 + lm) * 16;
            Bh[nt] = *(const bf16x8*)(rb + 16384 + idx);
            Bl[nt] = *(const bf16x8*)(rb + 24576 + idx);
        }
        asm volatile("s_waitcnt lgkmcnt(0)\ns_barrier" ::: "memory");
        __builtin_amdgcn_sched_barrier(0);
#pragma unroll
        for (int mt = 0; mt < 4; ++mt)
#pragma unroll
            for (int nt = 0; nt < 4; ++nt) {
                acc[mt][nt] = __builtin_amdgcn_mfma_f32_16x16x32_bf16(Ah[mt], Bh[nt], acc[mt][nt], 0, 0, 0);
                acc[mt][nt] = __builtin_amdgcn_mfma_f32_16x16x32_bf16(Ah[mt], Bl[nt], acc[mt][nt], 0, 0, 0);
                acc[mt][nt] = __builtin_amdgcn_mfma_f32_16x16x32_bf16(Al[mt], Bh[nt], acc[mt][nt], 0, 0, 0);
            }
    }

    // epilogue: 2 passes of 64 rows through a [64][132] exchange
    __syncthreads();
    float* S = (float*)smem;
#pragma unroll
    for (int h = 0; h < 2; ++h) {
        if ((w >> 1) == h) {
#pragma unroll
            for (int mt = 0; mt < 4; ++mt)
#pragma unroll
                for (int nt = 0; nt < 4; ++nt)
#pragma unroll
                    for (int r = 0; r < 4; ++r)
                        S[(mt * 16 + ko4 * 4 + r) * 132 + wc + nt * 16 + lm] = acc[mt][nt][r];
        }
        __syncthreads();
#pragma unroll
        for (int i = 0; i < 4; ++i) {
            const int task = tid * 4 + i;
            const int m = task >> 4, gr = task & 15;
            const int p0 = n0 + gr * 8;
            const float4 s0 = *(const float4*)&S[m * 132 + gr * 8];
            const float4 s1 = *(const float4*)&S[m * 132 + gr * 8 + 4];
            const float4 e0 = *(const float4*)&be[p0];
            const float4 e1 = *(const float4*)&be[p0 + 4];
            const float o[8] = {s0.x + e0.x, s0.y + e0.y, s0.z + e0.z, s0.w + e0.w,
                                s1.x + e1.x, s1.y + e1.y, s1.z + e1.z, s1.w + e1.w};
            u16 hb[8], lb[8];
#pragma unroll
            for (int e = 0; e < 8; ++e) {
                hb[e] = f2bf_rn(o[e]);
                lb[e] = f2bf_rn(o[e] - bf2f(hb[e]));
            }
            const int R = row0 + h * 64 + m;
            const int t = R % T_, b = R / T_;
            const size_t off = (size_t)t * 524288 + (((size_t)(p0 >> 3)) * 512 + b) * 16;
            *(uint4*)((char*)vphi + off) = pack8(hb);
            *(uint4*)((char*)vplo + off) = pack8(lb);
        }
        __syncthreads();
    }
}

// ---------------------------------------------------------------------------
// gx GEMM: Gx[t*B+b][n'] = vt' @ Wih'^T + b1g. NK=16, grid 6144.
// QUADRANT swizzle (R14-proven: FETCH 795->133 MB) + nt stores.
// ---------------------------------------------------------------------------
__global__ __launch_bounds__(256, 2)
void gx_mfma_kernel(const u16* __restrict__ vphi, const u16* __restrict__ vplo,
                    const u16* __restrict__ Wihhi, const u16* __restrict__ Wihlo,
                    const float* __restrict__ b1g, float* __restrict__ Gx)
{
    __shared__ char smem[65536];
    const int tid = threadIdx.x;
    const int xcd = blockIdx.x & 7, s_ = blockIdx.x >> 3;
    const int q  = s_ / 192;
    const int r_ = s_ % 192;
    const int by = q * 8 + (r_ & 7);
    const int tile = xcd * 24 + (r_ >> 3);
    const int t2 = tile >> 2, b0 = (tile & 3) * 128;
    const int n0 = by * 128;
    const int w = tid >> 6, l = tid & 63, lm = l & 15, ko4 = l >> 4;
    const int wr = (w >> 1) * 64, wc = (w & 1) * 64;

    const char* aS[4]; const char* bS[4]; int loff[4];
#pragma unroll
    for (int i = 0; i < 4; ++i) {
        const int j = w * 4 + i;
        const int ip = (j & 7) * 64 + l;
        const int ko = ip >> 7, rc = ip & 127;
        const char* ab = ((j >> 3) ? (const char*)vplo : (const char*)vphi)
                         + (size_t)t2 * 524288;
        aS[i] = ab + ((size_t)ko * 512 + b0 + rc) * 16;
        const char* bb = (j >> 3) ? (const char*)Wihlo : (const char*)Wihhi;
        bS[i] = bb + (size_t)by * 131072 + (size_t)ip * 16;
        loff[i] = j * 1024 + l * 16;
    }

    f32x4 acc[4][4] = {};
#pragma unroll
    for (int i = 0; i < 4; ++i) {
        gld16(aS[i], smem + loff[i]);
        gld16(bS[i], smem + 16384 + loff[i]);
    }

#pragma unroll 2
    for (int kk = 0; kk < 16; ++kk) {
        if (kk + 1 < 16) {
            const int bo = ((kk + 1) & 1) * 32768;
#pragma unroll
            for (int i = 0; i < 4; ++i) {
                gld16(aS[i] + (size_t)(kk + 1) * 32768, smem + bo + loff[i]);
                gld16(bS[i] + (size_t)(kk + 1) * 8192,  smem + bo + 16384 + loff[i]);
            }
            asm volatile("s_waitcnt vmcnt(8)\ns_barrier" ::: "memory");
        } else {
            asm volatile("s_waitcnt vmcnt(0)\ns_barrier" ::: "memory");
        }
        __builtin_amdgcn_sched_barrier(0);

        const char* rb = smem + (kk & 1) * 32768;
        bf16x8 Ah[4], Al[4], Bh[4], Bl[4];
#pragma unroll
        for (int mt = 0; mt < 4; ++mt) {
            const int idx = (ko4 * 128 + wr + mt * 16 + lm) * 16;
            Ah[mt] = *(const bf16x8*)(rb + idx);
            Al[mt] = *(const bf16x8*)(rb + 8192 + idx);
        }
#pragma unroll
        for (int nt = 0; nt < 4; ++nt) {
            const int idx = (ko4 * 128 + wc + nt * 16 + lm) * 16;
            Bh[nt] = *(const bf16x8*)(rb + 16384 + idx);
            Bl[nt] = *(const bf16x8*)(rb + 24576 + idx);
        }
        asm volatile("s_waitcnt lgkmcnt(0)\ns_barrier" ::: "memory");
        __builtin_amdgcn_sched_barrier(0);
#pragma unroll
        for (int mt = 0; mt < 4; ++mt)
#pragma unroll
            for (int nt = 0; nt < 4; ++nt) {
                acc[mt][nt] = __builtin_amdgcn_mfma_f32_16x16x32_bf16(Ah[mt], Bh[nt], acc[mt][nt], 0, 0, 0);
                acc[mt][nt] = __builtin_amdgcn_mfma_f32_16x16x32_bf16(Ah[mt], Bl[nt], acc[mt][nt], 0, 0, 0);
                acc[mt][nt] = __builtin_amdgcn_mfma_f32_16x16x32_bf16(Al[mt], Bh[nt], acc[mt][nt], 0, 0, 0);
            }
    }

    float bg[4];
#pragma unroll
    for (int nt = 0; nt < 4; ++nt) bg[nt] = b1g[n0 + wc + nt * 16 + lm];
    float* gbase = Gx + ((size_t)t2 * 512 + b0) * 4096 + n0;
#pragma unroll
    for (int mt = 0; mt < 4; ++mt)
#pragma unroll
        for (int r = 0; r < 4; ++r) {
            const int row = wr + mt * 16 + ko4 * 4 + r;
            float* rp = gbase + (size_t)row * 4096 + wc;
#pragma unroll
            for (int nt = 0; nt < 4; ++nt)
                __builtin_nontemporal_store(acc[mt][nt][r] + bg[nt], rp + nt * 16 + lm);
        }
}

// ---------------------------------------------------------------------------
// PERSISTENT LSTM step loop (hardened v2):
//  - grid 256 = 1 block/CU; LDS regions DISJOINT: [0,64K) stage ring,
//    [64K, 64K+33.8K) S-exchange, keepsm after — no aliasing hazards.
//  - after each grid.sync: explicit vmcnt(0)/lgkmcnt(0) drain + s_barrier
//    so every step starts with an empty VMEM FIFO (launch-identical).
//  - per-step math byte-identical to the R14-proven lstm_mfma_kernel.
// ---------------------------------------------------------------------------
__global__ __launch_bounds__(512, 1)
void lstm_persist_kernel(u16* __restrict__ hhiA, u16* __restrict__ hloA,
                         u16* __restrict__ hhiB, u16* __restrict__ hloB,
                         const u16* __restrict__ Whhhi, const u16* __restrict__ Whhlo,
                         const float* __restrict__ Gx,
                         const float* __restrict__ Lv,
                         float* __restrict__ PA, float* __restrict__ PB,
                         const float* __restrict__ wsh_v,
                         float* __restrict__ c1, float* __restrict__ out)
{
    cg::grid_group grid = cg::this_grid();
    __shared__ char smem[99584];                   // 64K ring | 33792 S | 256 keepsm
    float* S      = (float*)(smem + 65536);
    float* keepsm = (float*)(smem + 99328);
    const int tid = threadIdx.x;
    const int bid = blockIdx.x;
    const int xcd = bid & 7, slot = bid >> 3;
    const int by  = xcd * 4 + (slot & 3);
    const int bx  = slot >> 2;
    const int b0  = bx * 64;
    const int w = tid >> 6, l = tid & 63, lm = l & 15, ko4 = l >> 4;
    const int wr = (w >> 2) * 32, wc = (w & 3) * 32;
    const int t8 = tid & 255;
    const int koA = t8 >> 6, am = t8 & 63;

    const char* bhp = (const char*)Whhhi + (size_t)by * 262144
                      + ((size_t)(ko4 * 128 + wc + lm)) * 16;
    const char* blp = (const char*)Whhlo + (size_t)by * 262144
                      + ((size_t)(ko4 * 128 + wc + lm)) * 16;
    char* lbase = smem + (tid >> 8) * 4096 + t8 * 16;
    const size_t aoff = ((size_t)koA * 512 + b0 + am) * 16;

    const int h_l = tid & 31, rg = tid >> 5;
    const int hg  = by * 32 + h_l;
    const float wv = wsh_v[hg];
    const size_t hgbase = (((size_t)by * 4 + (h_l >> 3)) * 512) * 16 + (h_l & 7) * 2;

#pragma unroll 1
    for (int t = 0; t < T_; ++t) {
        const u16* hin_hi = (t & 1) ? hhiB : hhiA;
        const u16* hin_lo = (t & 1) ? hloB : hloA;
        u16* hout_hi      = (t & 1) ? hhiA : hhiB;
        u16* hout_lo      = (t & 1) ? hloA : hloB;
        const float* Pin  = (t & 1) ? PB : PA;
        float* Pout       = (t & 1) ? PA : PB;
        const float* Lv_t = Lv + t * B_;
        const float* Gxt  = Gx + (size_t)t * B_ * G4_;
        const char* aH = (const char*)(tid < 256 ? hin_hi : hin_lo) + aoff;

        f32x4 acc[2][2] = {};
        bf16x8 nBh[2][2], nBl[2][2], cBh[2][2], cBl[2][2], fAh[2][2], fAl[2][2];

        // prologue: stage(0)->buf0, stage(1)->buf1, B(0)
        gld16(aH + (size_t)0 * 32768, lbase);
        gld16(aH + (size_t)1 * 32768, lbase + 8192);
        gld16(aH + (size_t)2 * 32768, lbase + 16384);
        gld16(aH + (size_t)3 * 32768, lbase + 16384 + 8192);
#pragma unroll
        for (int h = 0; h < 2; ++h)
#pragma unroll
            for (int nt = 0; nt < 2; ++nt) {
                nBh[h][nt] = *(const bf16x8*)(bhp + (size_t)h * 8192 + nt * 256);
                nBl[h][nt] = *(const bf16x8*)(blp + (size_t)h * 8192 + nt * 256);
            }

        // keep[b] (after prologue issue; loads overlap the pipeline fill)
        if (tid < 64) {
            double s = (double)Lv_t[b0 + tid];
#pragma unroll
            for (int j = 0; j < 32; ++j) s += (double)Pin[j * B_ + b0 + tid];
            keepsm[tid] = (s > 0.0) ? 0.0f : 1.0f;
        }

#pragma unroll
        for (int kk = 0; kk < 16; ++kk) {
            if (kk == 15) asm volatile("s_waitcnt vmcnt(8)\ns_barrier" ::: "memory");
            else          asm volatile("s_waitcnt vmcnt(10)\ns_barrier" ::: "memory");
            __builtin_amdgcn_sched_barrier(0);
#pragma unroll
            for (int h = 0; h < 2; ++h)
#pragma unroll
                for (int nt = 0; nt < 2; ++nt) {
                    cBh[h][nt] = nBh[h][nt]; cBl[h][nt] = nBl[h][nt];
                }
            const char* rb = smem + (kk & 3) * 16384;
#pragma unroll
            for (int h = 0; h < 2; ++h)
#pragma unroll
                for (int mt = 0; mt < 2; ++mt) {
                    const int idx = (ko4 * 64 + wr + mt * 16 + lm) * 16;
                    fAh[h][mt] = *(const bf16x8*)(rb + h * 8192 + idx);
                    fAl[h][mt] = *(const bf16x8*)(rb + h * 8192 + 4096 + idx);
                }
            if (kk + 1 < 16) {
#pragma unroll
                for (int h = 0; h < 2; ++h)
#pragma unroll
                    for (int nt = 0; nt < 2; ++nt) {
                        nBh[h][nt] = *(const bf16x8*)(bhp + (size_t)(2 * (kk + 1) + h) * 8192 + nt * 256);
                        nBl[h][nt] = *(const bf16x8*)(blp + (size_t)(2 * (kk + 1) + h) * 8192 + nt * 256);
                    }
            }
            if (kk + 2 < 16) {
                char* db = smem + ((kk + 2) & 3) * 16384 + (tid >> 8) * 4096 + t8 * 16;
                gld16(aH + (size_t)(2 * (kk + 2) + 0) * 32768, db);
                gld16(aH + (size_t)(2 * (kk + 2) + 1) * 32768, db + 8192);
            }
#pragma unroll
            for (int h = 0; h < 2; ++h)
#pragma unroll
                for (int mt = 0; mt < 2; ++mt)
#pragma unroll
                    for (int nt = 0; nt < 2; ++nt) {
                        acc[mt][nt] = __builtin_amdgcn_mfma_f32_16x16x32_bf16(fAh[h][mt], cBh[h][nt], acc[mt][nt], 0, 0, 0);
                        acc[mt][nt] = __builtin_amdgcn_mfma_f32_16x16x32_bf16(fAh[h][mt], cBl[h][nt], acc[mt][nt], 0, 0, 0);
                        acc[mt][nt] = __builtin_amdgcn_mfma_f32_16x16x32_bf16(fAl[h][mt], cBh[h][nt], acc[mt][nt], 0, 0, 0);
                    }
        }
        asm volatile("s_waitcnt lgkmcnt(0)" ::: "memory");
        __builtin_amdgcn_sched_barrier(0);

        // prefetch Gx quadrant (plain loads, R14-proven)
        float4 gx[4];
#pragma unroll
        for (int i = 0; i < 4; ++i)
            gx[i] = *(const float4*)&Gxt[((size_t)b0 + rg * 4 + i) * 4096 + by * 128 + h_l * 4];

        __syncthreads();
        // S-exchange in DEDICATED region (no aliasing with stage ring)
#pragma unroll
        for (int mt = 0; mt < 2; ++mt)
#pragma unroll
            for (int nt = 0; nt < 2; ++nt) {
                const int col = wc + nt * 16 + lm;
#pragma unroll
                for (int r = 0; r < 4; ++r) {
                    const int row = wr + mt * 16 + ko4 * 4 + r;
                    S[row * 132 + col] = acc[mt][nt][r];
                }
            }
        __syncthreads();

#pragma unroll
        for (int i = 0; i < 4; ++i) {
            const int m = rg * 4 + i;
            const int b = b0 + m;
            const float4 g4 = *(const float4*)&S[m * 132 + h_l * 4];
            const float i_ = sigmoidf_(g4.x + gx[i].x);
            const float f_ = sigmoidf_(g4.y + gx[i].y);
            const float g_ = tanhf(g4.z + gx[i].z);
            const float o_ = sigmoidf_(g4.w + gx[i].w);
            const size_t off = (size_t)b * HID_ + hg;
            float cn = f_ * c1[off] + i_ * g_;
            float hn = o_ * tanhf(cn);
            const float kp = keepsm[m];
            cn *= kp; hn *= kp;
            c1[off] = cn;
            if (t == T_ - 1) out[off] = hn;
            const u16 hb = f2bf_rn(hn);
            const size_t hoff = hgbase + (size_t)b * 16;
            *(u16*)((char*)hout_hi + hoff) = hb;
            *(u16*)((char*)hout_lo + hoff) = f2bf_rn(hn - bf2f(hb));
            float pr = hn * wv;
            pr += __shfl_xor(pr, 16);
            pr += __shfl_xor(pr, 8);
            pr += __shfl_xor(pr, 4);
            pr += __shfl_xor(pr, 2);
            pr += __shfl_xor(pr, 1);
            if (h_l == 0) Pout[by * B_ + b] = pr;
        }

        __threadfence();
        grid.sync();
        __threadfence();
        // hardened step boundary: empty VMEM/LDS FIFO, all waves aligned
        asm volatile("s_waitcnt vmcnt(0) lgkmcnt(0)" ::: "memory");
        __builtin_amdgcn_sched_barrier(0);
        __builtin_amdgcn_s_barrier();
    }
}

// ---------------------------------------------------------------------------
extern "C" void kernel_launch(void* const* d_in, const int* in_sizes, int n_in,
                              void* d_out, int out_size, void* d_ws, size_t ws_size,
                              hipStream_t stream)
{
    const float* video = (const float*)d_in[0];
    const float* We    = (const float*)d_in[1];
    const float* be    = (const float*)d_in[2];
    const float* W1_ih = (const float*)d_in[3];
    const float* W1_hh = (const float*)d_in[4];
    const float* b1_ih = (const float*)d_in[5];
    const float* b1_hh = (const float*)d_in[6];
    // d_in[7], d_in[8] (W2_ih, W2_hh): dead — lstm2 never affects the output
    const float* Wsi   = (const float*)d_in[9];
    const float* Wsh   = (const float*)d_in[10];
    const float* bbd   = (const float*)d_in[11];
    const float* vs    = (const float*)d_in[12];
    float* out = (float*)d_out;

    char* p = (char*)d_ws;
    auto alloc = [&](size_t bytes) { char* r = p; p += (bytes + 255) & ~(size_t)255; return r; };
    u16* vidhi = (u16*)alloc((size_t)24576 * FRAME_ * 2);   // 96 MB
    u16* vidlo = (u16*)alloc((size_t)24576 * FRAME_ * 2);   // 96 MB
    u16* vphi  = (u16*)alloc((size_t)T_ * B_ * PROJ_ * 2);  // 24 MB
    u16* vplo  = (u16*)alloc((size_t)T_ * B_ * PROJ_ * 2);
    u16* Wehi  = (u16*)alloc((size_t)PROJ_ * FRAME_ * 2);
    u16* Welo  = (u16*)alloc((size_t)PROJ_ * FRAME_ * 2);
    u16* Wihhi = (u16*)alloc((size_t)G4_ * PROJ_ * 2);      // 4 MB
    u16* Wihlo = (u16*)alloc((size_t)G4_ * PROJ_ * 2);
    u16* Whhhi = (u16*)alloc((size_t)G4_ * HID_ * 2);       // 8 MB
    u16* Whhlo = (u16*)alloc((size_t)G4_ * HID_ * 2);
    float* Gx  = (float*)alloc((size_t)T_ * B_ * G4_ * 4);  // 402.7 MB
    float* c1  = (float*)alloc((size_t)B_ * HID_ * 4);
    u16* hhiA  = (u16*)alloc((size_t)B_ * HID_ * 2);
    u16* hhiB  = (u16*)alloc((size_t)B_ * HID_ * 2);
    u16* hloA  = (u16*)alloc((size_t)B_ * HID_ * 2);
    u16* hloB  = (u16*)alloc((size_t)B_ * HID_ * 2);
    double* wsi_vd = (double*)alloc(512 * 8);
    double* ud     = (double*)alloc(2048 * 8);
    double* ccd    = (double*)alloc(256);
    float* wsh_v = (float*)alloc(1024 * 4);
    float* Lv    = (float*)alloc((size_t)T_ * B_ * 4);
    float* PA    = (float*)alloc(32 * B_ * 4);
    float* PB    = (float*)alloc(32 * B_ * 4);
    float* b1g   = (float*)alloc(G4_ * 4);

    (void)hipMemsetAsync(c1,   0, (size_t)B_ * HID_ * 4, stream);
    (void)hipMemsetAsync(hhiA, 0, (size_t)B_ * HID_ * 2, stream);
    (void)hipMemsetAsync(hloA, 0, (size_t)B_ * HID_ * 2, stream);
    (void)hipMemsetAsync(PA,   0, 32 * B_ * 4, stream);
    (void)hipMemsetAsync(PB,   0, 32 * B_ * 4, stream);

    b1g_kernel<<<16, 256, 0, stream>>>(b1_ih, b1_hh, b1g);
    wvec_kernel<<<6, 256, 0, stream>>>(Wsi, Wsh, vs, wsi_vd, wsh_v);
    cc_kernel<<<1, 256, 0, stream>>>(be, wsi_vd, vs, bbd, ccd);
    u_kernel<<<8, 256, 0, stream>>>(We, wsi_vd, ud);
    wepack_kernel<<<dim3(64, 4), 256, 0, stream>>>(We, Wehi, Welo);
    wihpack_kernel<<<dim3(16, 32), 256, 0, stream>>>(W1_ih, Wihhi, Wihlo);
    whhpack_kernel<<<dim3(32, 32), 256, 0, stream>>>(W1_hh, Whhhi, Whhlo);
    vidpack_kernel<<<1536, 256, 0, stream>>>(video, ud, ccd, vidhi, vidlo, Lv);
    embed_mfma_kernel<<<768, 256, 0, stream>>>(vidhi, vidlo, Wehi, Welo, be, vphi, vplo);
    gx_mfma_kernel<<<6144, 256, 0, stream>>>(vphi, vplo, Wihhi, Wihlo, b1g, Gx);

    void* kargs[] = {(void*)&hhiA, (void*)&hloA, (void*)&hhiB, (void*)&hloB,
                     (void*)&Whhhi, (void*)&Whhlo, (void*)&Gx, (void*)&Lv,
                     (void*)&PA, (void*)&PB, (void*)&wsh_v, (void*)&c1, (void*)&out};
    (void)hipLaunchCooperativeKernel(lstm_persist_kernel, dim3(256), dim3(512),
                                     kargs, 0, stream);
}

// Round 16
// 1551.066 us; speedup vs baseline: 4.8987x; 4.8987x over previous
//
#include <hip/hip_runtime.h>

#define B_     512
#define T_     48
#define FRAME_ 2048
#define PROJ_  512
#define MID_   128
#define HID_   1024
#define G4_    4096

typedef unsigned short u16;
typedef __bf16 bf16x8 __attribute__((ext_vector_type(8)));
typedef float  f32x4  __attribute__((ext_vector_type(4)));

__device__ __forceinline__ float sigmoidf_(float x) {
    return 1.0f / (1.0f + expf(-x));
}
__device__ __forceinline__ u16 f2bf_rn(float f) {
    unsigned int u = __float_as_uint(f);
    u += 0x7fffu + ((u >> 16) & 1u);
    return (u16)(u >> 16);
}
__device__ __forceinline__ float bf2f(u16 s) {
    return __uint_as_float(((unsigned int)s) << 16);
}
__device__ __forceinline__ void gld16(const void* g, void* l) {
    __builtin_amdgcn_global_load_lds((const __attribute__((address_space(1))) void*)g,
                                     (__attribute__((address_space(3))) void*)l, 16, 0, 0);
}
__device__ __forceinline__ uint4 pack8(const u16* h) {
    return make_uint4((unsigned)h[0] | ((unsigned)h[1] << 16),
                      (unsigned)h[2] | ((unsigned)h[3] << 16),
                      (unsigned)h[4] | ((unsigned)h[5] << 16),
                      (unsigned)h[6] | ((unsigned)h[7] << 16));
}

// ---------------------------------------------------------------------------
// BD linearization precompute (exact fp64 path)
// ---------------------------------------------------------------------------
__global__ void wvec_kernel(const float* __restrict__ Wsi, const float* __restrict__ Wsh,
                            const float* __restrict__ vs,
                            double* __restrict__ wsi_vd, float* __restrict__ wsh_v)
{
    const int gid = blockIdx.x * 256 + threadIdx.x;
    if (gid < 512) {
        double s = 0.0;
        for (int mi = 0; mi < MID_; ++mi)
            s += (double)vs[mi] * (double)Wsi[(size_t)mi * PROJ_ + gid];
        wsi_vd[gid] = s;
    } else if (gid < 1536) {
        const int k = gid - 512;
        double s = 0.0;
        for (int mi = 0; mi < MID_; ++mi)
            s += (double)vs[mi] * (double)Wsh[(size_t)mi * HID_ + k];
        wsh_v[k] = (float)s;
    }
}

__global__ void cc_kernel(const float* __restrict__ be, const double* __restrict__ wsi_vd,
                          const float* __restrict__ vs, const float* __restrict__ bbd,
                          double* __restrict__ cc)
{
    __shared__ double red[256];
    const int tid = threadIdx.x;
    double s = 0.0;
    for (int p = tid; p < PROJ_; p += 256) s += (double)be[p] * wsi_vd[p];
    red[tid] = s;
    __syncthreads();
    for (int st = 128; st > 0; st >>= 1) {
        if (tid < st) red[tid] += red[tid + st];
        __syncthreads();
    }
    if (tid == 0) {
        double b = 0.0;
        for (int mi = 0; mi < MID_; ++mi) b += (double)vs[mi] * (double)bbd[mi];
        cc[0] = red[0] + b;
    }
}

__global__ void u_kernel(const float* __restrict__ We, const double* __restrict__ wsi_vd,
                         double* __restrict__ u)
{
    const int f = blockIdx.x * 256 + threadIdx.x;   // 2048
    double s = 0.0;
    for (int p = 0; p < PROJ_; ++p)
        s += wsi_vd[p] * (double)We[(size_t)p * FRAME_ + f];
    u[f] = s;
}

// ---------------------------------------------------------------------------
// vidpack: video fp32 -> packed bf16 hi/lo planes  vid'[g][row], g=k-octet
// Fused: Lv[t][b] = video[row]·u + cc   (fp64)
// ---------------------------------------------------------------------------
__global__ __launch_bounds__(256)
void vidpack_kernel(const float* __restrict__ video, const double* __restrict__ u,
                    const double* __restrict__ cc,
                    u16* __restrict__ phi, u16* __restrict__ plo,
                    float* __restrict__ Lv)
{
    __shared__ double red[16][17];
    const int tid = threadIdx.x;
    const int r   = tid & 15, kq = tid >> 4;
    const int row = blockIdx.x * 16 + r;
    const float* vr = video + (size_t)row * FRAME_;
    double s = 0.0;
#pragma unroll
    for (int j = 0; j < 16; ++j) {
        const int k0 = kq * 128 + j * 8;
        const float4 a = *(const float4*)&vr[k0];
        const float4 b = *(const float4*)&vr[k0 + 4];
        const float f[8] = {a.x, a.y, a.z, a.w, b.x, b.y, b.z, b.w};
        s += (double)f[0]*u[k0+0] + (double)f[1]*u[k0+1] + (double)f[2]*u[k0+2]
           + (double)f[3]*u[k0+3] + (double)f[4]*u[k0+4] + (double)f[5]*u[k0+5]
           + (double)f[6]*u[k0+6] + (double)f[7]*u[k0+7];
        u16 h[8], l[8];
#pragma unroll
        for (int e = 0; e < 8; ++e) {
            h[e] = f2bf_rn(f[e]);
            l[e] = f2bf_rn(f[e] - bf2f(h[e]));
        }
        const int g = kq * 16 + j;
        const size_t off = ((size_t)g * 24576 + row) * 16;
        *(uint4*)((char*)phi + off) = pack8(h);
        *(uint4*)((char*)plo + off) = pack8(l);
    }
    red[r][kq] = s;
    __syncthreads();
    if (tid < 16) {
        double t = 0.0;
#pragma unroll
        for (int q = 0; q < 16; ++q) t += red[tid][q];
        const int rw = blockIdx.x * 16 + tid;
        Lv[(rw % T_) * B_ + rw / T_] = (float)(t + cc[0]);
    }
}

// ---------------------------------------------------------------------------
// wepack: We -> packed planes  We'[by][kk][ko*128+n]
// ---------------------------------------------------------------------------
__global__ void wepack_kernel(const float* __restrict__ We,
                              u16* __restrict__ phi, u16* __restrict__ plo)
{
    const int kk = blockIdx.x, by = blockIdx.y, tid = threadIdx.x;
#pragma unroll
    for (int pass = 0; pass < 2; ++pass) {
        const int g = tid + pass * 256;
        const int ko = g >> 7, n = g & 127;
        const int p = by * 128 + n;
        const int k = kk * 32 + ko * 8;
        const float4 a = *(const float4*)&We[(size_t)p * FRAME_ + k];
        const float4 b = *(const float4*)&We[(size_t)p * FRAME_ + k + 4];
        const float f[8] = {a.x, a.y, a.z, a.w, b.x, b.y, b.z, b.w};
        u16 h[8], l[8];
#pragma unroll
        for (int e = 0; e < 8; ++e) {
            h[e] = f2bf_rn(f[e]);
            l[e] = f2bf_rn(f[e] - bf2f(h[e]));
        }
        const size_t off = (((size_t)by * 64 + kk) * 512 + g) * 16;
        *(uint4*)((char*)phi + off) = pack8(h);
        *(uint4*)((char*)plo + off) = pack8(l);
    }
}

// ---------------------------------------------------------------------------
// wihpack / whhpack: W1 (gate-interleaved n) -> packed planes
// ---------------------------------------------------------------------------
__global__ void wihpack_kernel(const float* __restrict__ Wih,
                               u16* __restrict__ phi, u16* __restrict__ plo)
{
    const int kk = blockIdx.x, by = blockIdx.y, tid = threadIdx.x;
#pragma unroll
    for (int pass = 0; pass < 2; ++pass) {
        const int g = tid + pass * 256;
        const int ko = g >> 7, n = g & 127;
        const int gate = n & 3, hl = n >> 2;
        const int srow = gate * HID_ + by * 32 + hl;
        const int k = kk * 32 + ko * 8;
        const float4 a = *(const float4*)&Wih[(size_t)srow * PROJ_ + k];
        const float4 b = *(const float4*)&Wih[(size_t)srow * PROJ_ + k + 4];
        const float f[8] = {a.x, a.y, a.z, a.w, b.x, b.y, b.z, b.w};
        u16 h[8], l[8];
#pragma unroll
        for (int e = 0; e < 8; ++e) {
            h[e] = f2bf_rn(f[e]);
            l[e] = f2bf_rn(f[e] - bf2f(h[e]));
        }
        const size_t off = (((size_t)by * 16 + kk) * 512 + g) * 16;
        *(uint4*)((char*)phi + off) = pack8(h);
        *(uint4*)((char*)plo + off) = pack8(l);
    }
}

__global__ void whhpack_kernel(const float* __restrict__ Whh,
                               u16* __restrict__ phi, u16* __restrict__ plo)
{
    const int kk = blockIdx.x, by = blockIdx.y, tid = threadIdx.x;
#pragma unroll
    for (int pass = 0; pass < 2; ++pass) {
        const int g = tid + pass * 256;
        const int ko = g >> 7, n = g & 127;
        const int gate = n & 3, hl = n >> 2;
        const int srow = gate * HID_ + by * 32 + hl;
        const int k = kk * 32 + ko * 8;
        const float4 a = *(const float4*)&Whh[(size_t)srow * HID_ + k];
        const float4 b = *(const float4*)&Whh[(size_t)srow * HID_ + k + 4];
        const float f[8] = {a.x, a.y, a.z, a.w, b.x, b.y, b.z, b.w};
        u16 h[8], l[8];
#pragma unroll
        for (int e = 0; e < 8; ++e) {
            h[e] = f2bf_rn(f[e]);
            l[e] = f2bf_rn(f[e] - bf2f(h[e]));
        }
        const size_t off = (((size_t)by * 32 + kk) * 512 + g) * 16;
        *(uint4*)((char*)phi + off) = pack8(h);
        *(uint4*)((char*)plo + off) = pack8(l);
    }
}

// b1g: gate-interleaved bias vector (added once into Gx)
__global__ void b1g_kernel(const float* __restrict__ bih, const float* __restrict__ bhh,
                           float* __restrict__ b1g)
{
    const int n = blockIdx.x * 256 + threadIdx.x;   // 4096
    const int by = n >> 7, nl = n & 127;
    const int gate = nl & 3, hl = nl >> 2;
    const int src = gate * HID_ + by * 32 + hl;
    b1g[n] = bih[src] + bhh[src];
}

// ===========================================================================
// 128x128-tile GEMMs: 256 threads = 4 waves, 64x64 wave tiles,
// A+B LDS double-buffered, 2-barrier protocol per iter.
// ===========================================================================

// ---------------------------------------------------------------------------
// embed GEMM: vt = video @ We^T + be -> vt' packed planes. NK=64, grid 768.
// ---------------------------------------------------------------------------
__global__ __launch_bounds__(256, 2)
void embed_mfma_kernel(const u16* __restrict__ Ahi_g, const u16* __restrict__ Alo_g,
                       const u16* __restrict__ Bhi_g, const u16* __restrict__ Blo_g,
                       const float* __restrict__ be,
                       u16* __restrict__ vphi, u16* __restrict__ vplo)
{
    __shared__ char smem[65536];
    const int tid = threadIdx.x;
    const int xcd = blockIdx.x & 7, s_ = blockIdx.x >> 3;   // 768 blocks, s_<96
    const int by = s_ & 3, bx = xcd * 24 + (s_ >> 2);
    const int n0 = by * 128, row0 = bx * 128;
    const int w = tid >> 6, l = tid & 63, lm = l & 15, ko4 = l >> 4;
    const int wr = (w >> 1) * 64, wc = (w & 1) * 64;

    const char* aS[4]; const char* bS[4]; int loff[4];
#pragma unroll
    for (int i = 0; i < 4; ++i) {
        const int j = w * 4 + i;                 // 0..15
        const int ip = (j & 7) * 64 + l;         // 0..511 within plane
        const int ko = ip >> 7, rc = ip & 127;
        const char* ab = (j >> 3) ? (const char*)Alo_g : (const char*)Ahi_g;
        aS[i] = ab + ((size_t)ko * 24576 + row0 + rc) * 16;
        const char* bb = (j >> 3) ? (const char*)Blo_g : (const char*)Bhi_g;
        bS[i] = bb + (size_t)by * 524288 + (size_t)ip * 16;
        loff[i] = j * 1024 + l * 16;
    }

    f32x4 acc[4][4] = {};
#pragma unroll
    for (int i = 0; i < 4; ++i) {                // stage(0) -> buf0
        gld16(aS[i], smem + loff[i]);
        gld16(bS[i], smem + 16384 + loff[i]);
    }

#pragma unroll 2
    for (int kk = 0; kk < 64; ++kk) {
        if (kk + 1 < 64) {
            const int bo = ((kk + 1) & 1) * 32768;
#pragma unroll
            for (int i = 0; i < 4; ++i) {
                gld16(aS[i] + (size_t)(kk + 1) * 1572864, smem + bo + loff[i]);
                gld16(bS[i] + (size_t)(kk + 1) * 8192,    smem + bo + 16384 + loff[i]);
            }
            asm volatile("s_waitcnt vmcnt(8)\ns_barrier" ::: "memory");
        } else {
            asm volatile("s_waitcnt vmcnt(0)\ns_barrier" ::: "memory");
        }
        __builtin_amdgcn_sched_barrier(0);

        const char* rb = smem + (kk & 1) * 32768;
        bf16x8 Ah[4], Al[4], Bh[4], Bl[4];
#pragma unroll
        for (int mt = 0; mt < 4; ++mt) {
            const int idx = (ko4 * 128 + wr + mt * 16 + lm) * 16;
            Ah[mt] = *(const bf16x8*)(rb + idx);
            Al[mt] = *(const bf16x8*)(rb + 8192 + idx);
        }
#pragma unroll
        for (int nt = 0; nt < 4; ++nt) {
            const int idx = (ko4 * 128 + wc + nt * 16 + lm) * 16;
            Bh[nt] = *(const bf16x8*)(rb + 16384 + idx);
            Bl[nt] = *(const bf16x8*)(rb + 24576 + idx);
        }
        asm volatile("s_waitcnt lgkmcnt(0)\ns_barrier" ::: "memory");
        __builtin_amdgcn_sched_barrier(0);
#pragma unroll
        for (int mt = 0; mt < 4; ++mt)
#pragma unroll
            for (int nt = 0; nt < 4; ++nt) {
                acc[mt][nt] = __builtin_amdgcn_mfma_f32_16x16x32_bf16(Ah[mt], Bh[nt], acc[mt][nt], 0, 0, 0);
                acc[mt][nt] = __builtin_amdgcn_mfma_f32_16x16x32_bf16(Ah[mt], Bl[nt], acc[mt][nt], 0, 0, 0);
                acc[mt][nt] = __builtin_amdgcn_mfma_f32_16x16x32_bf16(Al[mt], Bh[nt], acc[mt][nt], 0, 0, 0);
            }
    }

    // epilogue: 2 passes of 64 rows through a [64][132] exchange
    __syncthreads();
    float* S = (float*)smem;
#pragma unroll
    for (int h = 0; h < 2; ++h) {
        if ((w >> 1) == h) {
#pragma unroll
            for (int mt = 0; mt < 4; ++mt)
#pragma unroll
                for (int nt = 0; nt < 4; ++nt)
#pragma unroll
                    for (int r = 0; r < 4; ++r)
                        S[(mt * 16 + ko4 * 4 + r) * 132 + wc + nt * 16 + lm] = acc[mt][nt][r];
        }
        __syncthreads();
#pragma unroll
        for (int i = 0; i < 4; ++i) {
            const int task = tid * 4 + i;        // 0..1023 (same m for all i)
            const int m = task >> 4, gr = task & 15;
            const int p0 = n0 + gr * 8;
            const float4 s0 = *(const float4*)&S[m * 132 + gr * 8];
            const float4 s1 = *(const float4*)&S[m * 132 + gr * 8 + 4];
            const float4 e0 = *(const float4*)&be[p0];
            const float4 e1 = *(const float4*)&be[p0 + 4];
            const float o[8] = {s0.x + e0.x, s0.y + e0.y, s0.z + e0.z, s0.w + e0.w,
                                s1.x + e1.x, s1.y + e1.y, s1.z + e1.z, s1.w + e1.w};
            u16 hb[8], lb[8];
#pragma unroll
            for (int e = 0; e < 8; ++e) {
                hb[e] = f2bf_rn(o[e]);
                lb[e] = f2bf_rn(o[e] - bf2f(hb[e]));
            }
            const int R = row0 + h * 64 + m;
            const int t = R % T_, b = R / T_;
            const size_t off = (size_t)t * 524288 + (((size_t)(p0 >> 3)) * 512 + b) * 16;
            *(uint4*)((char*)vphi + off) = pack8(hb);
            *(uint4*)((char*)vplo + off) = pack8(lb);
        }
        __syncthreads();
    }
}

// ---------------------------------------------------------------------------
// gx GEMM: Gx[t*B+b][n'] = vt' @ Wih'^T + b1g. NK=16, grid 6144.
// QUADRANT swizzle: cohort = 8 by x 8 tiles (B 2MB + A 2MB fits 4MB L2);
// A/B totals (49+8 MB) are L3-resident across quadrants. nt-stores kept.
// ---------------------------------------------------------------------------
__global__ __launch_bounds__(256, 2)
void gx_mfma_kernel(const u16* __restrict__ vphi, const u16* __restrict__ vplo,
                    const u16* __restrict__ Wihhi, const u16* __restrict__ Wihlo,
                    const float* __restrict__ b1g, float* __restrict__ Gx)
{
    __shared__ char smem[65536];
    const int tid = threadIdx.x;
    const int xcd = blockIdx.x & 7, s_ = blockIdx.x >> 3;   // 6144 blocks, s_<768
    const int q  = s_ / 192;                                 // by-octant
    const int r_ = s_ % 192;
    const int by = q * 8 + (r_ & 7);                         // [0,32)
    const int tile = xcd * 24 + (r_ >> 3);                   // [0,192)
    const int t2 = tile >> 2, b0 = (tile & 3) * 128;
    const int n0 = by * 128;
    const int w = tid >> 6, l = tid & 63, lm = l & 15, ko4 = l >> 4;
    const int wr = (w >> 1) * 64, wc = (w & 1) * 64;

    const char* aS[4]; const char* bS[4]; int loff[4];
#pragma unroll
    for (int i = 0; i < 4; ++i) {
        const int j = w * 4 + i;
        const int ip = (j & 7) * 64 + l;
        const int ko = ip >> 7, rc = ip & 127;
        const char* ab = ((j >> 3) ? (const char*)vplo : (const char*)vphi)
                         + (size_t)t2 * 524288;
        aS[i] = ab + ((size_t)ko * 512 + b0 + rc) * 16;
        const char* bb = (j >> 3) ? (const char*)Wihlo : (const char*)Wihhi;
        bS[i] = bb + (size_t)by * 131072 + (size_t)ip * 16;
        loff[i] = j * 1024 + l * 16;
    }

    f32x4 acc[4][4] = {};
#pragma unroll
    for (int i = 0; i < 4; ++i) {
        gld16(aS[i], smem + loff[i]);
        gld16(bS[i], smem + 16384 + loff[i]);
    }

#pragma unroll 2
    for (int kk = 0; kk < 16; ++kk) {
        if (kk + 1 < 16) {
            const int bo = ((kk + 1) & 1) * 32768;
#pragma unroll
            for (int i = 0; i < 4; ++i) {
                gld16(aS[i] + (size_t)(kk + 1) * 32768, smem + bo + loff[i]);
                gld16(bS[i] + (size_t)(kk + 1) * 8192,  smem + bo + 16384 + loff[i]);
            }
            asm volatile("s_waitcnt vmcnt(8)\ns_barrier" ::: "memory");
        } else {
            asm volatile("s_waitcnt vmcnt(0)\ns_barrier" ::: "memory");
        }
        __builtin_amdgcn_sched_barrier(0);

        const char* rb = smem + (kk & 1) * 32768;
        bf16x8 Ah[4], Al[4], Bh[4], Bl[4];
#pragma unroll
        for (int mt = 0; mt < 4; ++mt) {
            const int idx = (ko4 * 128 + wr + mt * 16 + lm) * 16;
            Ah[mt] = *(const bf16x8*)(rb + idx);
            Al[mt] = *(const bf16x8*)(rb + 8192 + idx);
        }
#pragma unroll
        for (int nt = 0; nt < 4; ++nt) {
            const int idx = (ko4 * 128 + wc + nt * 16 + lm) * 16;
            Bh[nt] = *(const bf16x8*)(rb + 16384 + idx);
            Bl[nt] = *(const bf16x8*)(rb + 24576 + idx);
        }
        asm volatile("s_waitcnt lgkmcnt(0)\ns_barrier" ::: "memory");
        __builtin_amdgcn_sched_barrier(0);
#pragma unroll
        for (int mt = 0; mt < 4; ++mt)
#pragma unroll
            for (int nt = 0; nt < 4; ++nt) {
                acc[mt][nt] = __builtin_amdgcn_mfma_f32_16x16x32_bf16(Ah[mt], Bh[nt], acc[mt][nt], 0, 0, 0);
                acc[mt][nt] = __builtin_amdgcn_mfma_f32_16x16x32_bf16(Ah[mt], Bl[nt], acc[mt][nt], 0, 0, 0);
                acc[mt][nt] = __builtin_amdgcn_mfma_f32_16x16x32_bf16(Al[mt], Bh[nt], acc[mt][nt], 0, 0, 0);
            }
    }

    // epilogue: direct NON-TEMPORAL stores (evict-first)
    float bg[4];
#pragma unroll
    for (int nt = 0; nt < 4; ++nt) bg[nt] = b1g[n0 + wc + nt * 16 + lm];
    float* gbase = Gx + ((size_t)t2 * 512 + b0) * 4096 + n0;
#pragma unroll
    for (int mt = 0; mt < 4; ++mt)
#pragma unroll
        for (int r = 0; r < 4; ++r) {
            const int row = wr + mt * 16 + ko4 * 4 + r;
            float* rp = gbase + (size_t)row * 4096 + wc;
#pragma unroll
            for (int nt = 0; nt < 4; ++nt)
                __builtin_nontemporal_store(acc[mt][nt][r] + bg[nt], rp + nt * 16 + lm);
        }
}

// ---------------------------------------------------------------------------
// LSTM1 step: gates = Gx[t] + h @ Whh'^T ; BK=64 -> NK=16, grid 256.
// 4 x 16KB A-ring (halves: 32-k groups 2kk, 2kk+1), B direct-from-global.
// vmcnt queue at iter gate: [B(kk)=8, stage(kk+1)=2] -> vmcnt(10); last: 8.
// (R10/R14-proven kernel, byte-identical.)
// ---------------------------------------------------------------------------
__global__ __launch_bounds__(512, 2)
void lstm_mfma_kernel(const u16* __restrict__ hhi,  const u16* __restrict__ hlo,
                      const u16* __restrict__ Whhhi, const u16* __restrict__ Whhlo,
                      const float* __restrict__ Gxt,
                      const float* __restrict__ Lv_t,
                      const float* __restrict__ Pin,
                      float* __restrict__ Pout,
                      const float* __restrict__ wsh_v,
                      float* __restrict__ c1, float* __restrict__ h1o,
                      u16* __restrict__ hhio, u16* __restrict__ hloo)
{
    __shared__ char smem[65792];               // 4 x 16KB bufs + keepsm
    float* keepsm = (float*)(smem + 65536);
    const int tid = threadIdx.x;
    const int bid = blockIdx.x;
    const int xcd = bid & 7, slot = bid >> 3;
    const int by  = xcd * 4 + (slot & 3);
    const int bx  = slot >> 2;
    const int b0  = bx * 64;
    const int w = tid >> 6, l = tid & 63, lm = l & 15, ko4 = l >> 4;
    const int wr = (w >> 2) * 32, wc = (w & 3) * 32;
    const int t8 = tid & 255;
    const int koA = t8 >> 6, am = t8 & 63;

    if (tid < 64) {
        double s = (double)Lv_t[b0 + tid];
#pragma unroll
        for (int j = 0; j < 32; ++j) s += (double)Pin[j * B_ + b0 + tid];
        keepsm[tid] = (s > 0.0) ? 0.0f : 1.0f;
    }

    const char* aH = (const char*)(tid < 256 ? hhi : hlo)
                     + ((size_t)koA * 512 + b0 + am) * 16;
    const char* bh = (const char*)Whhhi + (size_t)by * 262144
                     + ((size_t)(ko4 * 128 + wc + lm)) * 16;
    const char* bl = (const char*)Whhlo + (size_t)by * 262144
                     + ((size_t)(ko4 * 128 + wc + lm)) * 16;
    char* lbase = smem + (tid >> 8) * 4096 + t8 * 16;   // position within an 8KB half

    f32x4 acc[2][2] = {};
    bf16x8 nBh[2][2], nBl[2][2], cBh[2][2], cBl[2][2], fAh[2][2], fAl[2][2];

    // prologue: stage(0) -> buf0 (groups 0,1), stage(1) -> buf1 (groups 2,3), B(0)
    gld16(aH + (size_t)0 * 32768, lbase);
    gld16(aH + (size_t)1 * 32768, lbase + 8192);
    gld16(aH + (size_t)2 * 32768, lbase + 16384);
    gld16(aH + (size_t)3 * 32768, lbase + 16384 + 8192);
#pragma unroll
    for (int h = 0; h < 2; ++h)
#pragma unroll
        for (int nt = 0; nt < 2; ++nt) {
            nBh[h][nt] = *(const bf16x8*)(bh + (size_t)h * 8192 + nt * 256);
            nBl[h][nt] = *(const bf16x8*)(bl + (size_t)h * 8192 + nt * 256);
        }

#pragma unroll
    for (int kk = 0; kk < 16; ++kk) {
        if (kk == 15) asm volatile("s_waitcnt vmcnt(8)\ns_barrier" ::: "memory");
        else          asm volatile("s_waitcnt vmcnt(10)\ns_barrier" ::: "memory");
        __builtin_amdgcn_sched_barrier(0);
#pragma unroll
        for (int h = 0; h < 2; ++h)
#pragma unroll
            for (int nt = 0; nt < 2; ++nt) {
                cBh[h][nt] = nBh[h][nt]; cBl[h][nt] = nBl[h][nt];
            }
        const char* rb = smem + (kk & 3) * 16384;
#pragma unroll
        for (int h = 0; h < 2; ++h)
#pragma unroll
            for (int mt = 0; mt < 2; ++mt) {
                const int idx = (ko4 * 64 + wr + mt * 16 + lm) * 16;
                fAh[h][mt] = *(const bf16x8*)(rb + h * 8192 + idx);
                fAl[h][mt] = *(const bf16x8*)(rb + h * 8192 + 4096 + idx);
            }
        if (kk + 1 < 16) {
#pragma unroll
            for (int h = 0; h < 2; ++h)
#pragma unroll
                for (int nt = 0; nt < 2; ++nt) {
                    nBh[h][nt] = *(const bf16x8*)(bh + (size_t)(2 * (kk + 1) + h) * 8192 + nt * 256);
                    nBl[h][nt] = *(const bf16x8*)(bl + (size_t)(2 * (kk + 1) + h) * 8192 + nt * 256);
                }
        }
        if (kk + 2 < 16) {
            char* db = smem + ((kk + 2) & 3) * 16384 + (tid >> 8) * 4096 + t8 * 16;
            gld16(aH + (size_t)(2 * (kk + 2) + 0) * 32768, db);
            gld16(aH + (size_t)(2 * (kk + 2) + 1) * 32768, db + 8192);
        }
#pragma unroll
        for (int h = 0; h < 2; ++h)
#pragma unroll
            for (int mt = 0; mt < 2; ++mt)
#pragma unroll
                for (int nt = 0; nt < 2; ++nt) {
                    acc[mt][nt] = __builtin_amdgcn_mfma_f32_16x16x32_bf16(fAh[h][mt], cBh[h][nt], acc[mt][nt], 0, 0, 0);
                    acc[mt][nt] = __builtin_amdgcn_mfma_f32_16x16x32_bf16(fAh[h][mt], cBl[h][nt], acc[mt][nt], 0, 0, 0);
                    acc[mt][nt] = __builtin_amdgcn_mfma_f32_16x16x32_bf16(fAl[h][mt], cBh[h][nt], acc[mt][nt], 0, 0, 0);
                }
    }
    asm volatile("s_waitcnt lgkmcnt(0)" ::: "memory");
    __builtin_amdgcn_sched_barrier(0);

    const int h_l = tid & 31, rg = tid >> 5;
    const int hg  = by * 32 + h_l;
    float4 gx[4];
#pragma unroll
    for (int i = 0; i < 4; ++i)
        gx[i] = *(const float4*)&Gxt[((size_t)b0 + rg * 4 + i) * 4096 + by * 128 + h_l * 4];

    __syncthreads();
    float* S = (float*)smem;   // [64][132]
#pragma unroll
    for (int mt = 0; mt < 2; ++mt)
#pragma unroll
        for (int nt = 0; nt < 2; ++nt) {
            const int col = wc + nt * 16 + lm;
#pragma unroll
            for (int r = 0; r < 4; ++r) {
                const int row = wr + mt * 16 + ko4 * 4 + r;
                S[row * 132 + col] = acc[mt][nt][r];
            }
        }
    __syncthreads();

    const float wv = wsh_v[hg];
    const size_t hgbase = (((size_t)by * 4 + (h_l >> 3)) * 512) * 16 + (h_l & 7) * 2;
#pragma unroll
    for (int i = 0; i < 4; ++i) {
        const int m = rg * 4 + i;
        const int b = b0 + m;
        const float4 g4 = *(const float4*)&S[m * 132 + h_l * 4];
        const float i_ = sigmoidf_(g4.x + gx[i].x);
        const float f_ = sigmoidf_(g4.y + gx[i].y);
        const float g_ = tanhf(g4.z + gx[i].z);
        const float o_ = sigmoidf_(g4.w + gx[i].w);
        const size_t off = (size_t)b * HID_ + hg;
        float cn = f_ * c1[off] + i_ * g_;
        float hn = o_ * tanhf(cn);
        const float kp = keepsm[m];
        cn *= kp; hn *= kp;
        c1[off] = cn;
        if (h1o) h1o[off] = hn;
        const u16 hb = f2bf_rn(hn);
        const size_t hoff = hgbase + (size_t)b * 16;
        *(u16*)((char*)hhio + hoff) = hb;
        *(u16*)((char*)hloo + hoff) = f2bf_rn(hn - bf2f(hb));
        float pr = hn * wv;
        pr += __shfl_xor(pr, 16);
        pr += __shfl_xor(pr, 8);
        pr += __shfl_xor(pr, 4);
        pr += __shfl_xor(pr, 2);
        pr += __shfl_xor(pr, 1);
        if (h_l == 0) Pout[by * B_ + b] = pr;
    }
}

// ---------------------------------------------------------------------------
extern "C" void kernel_launch(void* const* d_in, const int* in_sizes, int n_in,
                              void* d_out, int out_size, void* d_ws, size_t ws_size,
                              hipStream_t stream)
{
    const float* video = (const float*)d_in[0];
    const float* We    = (const float*)d_in[1];
    const float* be    = (const float*)d_in[2];
    const float* W1_ih = (const float*)d_in[3];
    const float* W1_hh = (const float*)d_in[4];
    const float* b1_ih = (const float*)d_in[5];
    const float* b1_hh = (const float*)d_in[6];
    // d_in[7], d_in[8] (W2_ih, W2_hh): dead — lstm2 never affects the output
    const float* Wsi   = (const float*)d_in[9];
    const float* Wsh   = (const float*)d_in[10];
    const float* bbd   = (const float*)d_in[11];
    const float* vs    = (const float*)d_in[12];
    float* out = (float*)d_out;

    char* p = (char*)d_ws;
    auto alloc = [&](size_t bytes) { char* r = p; p += (bytes + 255) & ~(size_t)255; return r; };
    u16* vidhi = (u16*)alloc((size_t)24576 * FRAME_ * 2);   // 96 MB
    u16* vidlo = (u16*)alloc((size_t)24576 * FRAME_ * 2);   // 96 MB
    u16* vphi  = (u16*)alloc((size_t)T_ * B_ * PROJ_ * 2);  // 24 MB
    u16* vplo  = (u16*)alloc((size_t)T_ * B_ * PROJ_ * 2);
    u16* Wehi  = (u16*)alloc((size_t)PROJ_ * FRAME_ * 2);
    u16* Welo  = (u16*)alloc((size_t)PROJ_ * FRAME_ * 2);
    u16* Wihhi = (u16*)alloc((size_t)G4_ * PROJ_ * 2);      // 4 MB
    u16* Wihlo = (u16*)alloc((size_t)G4_ * PROJ_ * 2);
    u16* Whhhi = (u16*)alloc((size_t)G4_ * HID_ * 2);       // 8 MB
    u16* Whhlo = (u16*)alloc((size_t)G4_ * HID_ * 2);
    float* Gx  = (float*)alloc((size_t)T_ * B_ * G4_ * 4);  // 402.7 MB
    float* c1  = (float*)alloc((size_t)B_ * HID_ * 4);
    u16* hhiA  = (u16*)alloc((size_t)B_ * HID_ * 2);
    u16* hhiB  = (u16*)alloc((size_t)B_ * HID_ * 2);
    u16* hloA  = (u16*)alloc((size_t)B_ * HID_ * 2);
    u16* hloB  = (u16*)alloc((size_t)B_ * HID_ * 2);
    double* wsi_vd = (double*)alloc(512 * 8);
    double* ud     = (double*)alloc(2048 * 8);
    double* ccd    = (double*)alloc(256);
    float* wsh_v = (float*)alloc(1024 * 4);
    float* Lv    = (float*)alloc((size_t)T_ * B_ * 4);
    float* PA    = (float*)alloc(32 * B_ * 4);
    float* PB    = (float*)alloc(32 * B_ * 4);
    float* b1g   = (float*)alloc(G4_ * 4);

    (void)hipMemsetAsync(c1,   0, (size_t)B_ * HID_ * 4, stream);
    (void)hipMemsetAsync(hhiA, 0, (size_t)B_ * HID_ * 2, stream);
    (void)hipMemsetAsync(hloA, 0, (size_t)B_ * HID_ * 2, stream);
    (void)hipMemsetAsync(PA,   0, 32 * B_ * 4, stream);

    b1g_kernel<<<16, 256, 0, stream>>>(b1_ih, b1_hh, b1g);
    wvec_kernel<<<6, 256, 0, stream>>>(Wsi, Wsh, vs, wsi_vd, wsh_v);
    cc_kernel<<<1, 256, 0, stream>>>(be, wsi_vd, vs, bbd, ccd);
    u_kernel<<<8, 256, 0, stream>>>(We, wsi_vd, ud);
    wepack_kernel<<<dim3(64, 4), 256, 0, stream>>>(We, Wehi, Welo);
    wihpack_kernel<<<dim3(16, 32), 256, 0, stream>>>(W1_ih, Wihhi, Wihlo);
    whhpack_kernel<<<dim3(32, 32), 256, 0, stream>>>(W1_hh, Whhhi, Whhlo);
    vidpack_kernel<<<1536, 256, 0, stream>>>(video, ud, ccd, vidhi, vidlo, Lv);
    embed_mfma_kernel<<<768, 256, 0, stream>>>(vidhi, vidlo, Wehi, Welo, be, vphi, vplo);
    gx_mfma_kernel<<<6144, 256, 0, stream>>>(vphi, vplo, Wihhi, Wihlo, b1g, Gx);

    u16* hhi_in = hhiA; u16* hhi_out = hhiB;
    u16* hlo_in = hloA; u16* hlo_out = hloB;
    float* Pin = PA; float* Pout = PB;

    for (int t = 0; t < T_; ++t) {
        float* ho = (t == T_ - 1) ? out : nullptr;
        lstm_mfma_kernel<<<256, 512, 0, stream>>>(hhi_in, hlo_in, Whhhi, Whhlo,
                                                  Gx + (size_t)t * B_ * G4_,
                                                  Lv + t * B_, Pin, Pout, wsh_v,
                                                  c1, ho, hhi_out, hlo_out);
        { u16* tmp = hhi_in; hhi_in = hhi_out; hhi_out = tmp; }
        { u16* tmp = hlo_in; hlo_in = hlo_out; hlo_out = tmp; }
        { float* tmp = Pin; Pin = Pout; Pout = tmp; }
    }
}